// Round 16
// baseline (130.627 us; speedup 1.0000x reference)
//
#include <hip/hip_runtime.h>
#include <hip/hip_bf16.h>
#include <stdint.h>
#include <math.h>

// MLA: B=2, L=2048, D=1024, H=16, DH=64, DC=512. All f32 in/out; bf16 MFMA inside.
// SESSION LESSONS:
//  (R11) LDS stride for bf16 vector ds ops MUST be a multiple of 8 elements.
//  (R8/R12/R13) attn per-wave shape closed: 16q/wave x 4-wave blocks.
//  (R3) no runtime-indexed LDS buffers; (R6/R11) no hot-loop branches.
//  (R14) GEMM BK=64 + XOR swizzle: conflict-free frag reads, half barriers.
//  (R15) static dbuf neutral (latency hidden == occupancy lost): single buf.
//  (R16) attn is latency-chain-bound at 2.5-way block overlap; grid was the
//        residency cap (4 blocks/CU avail vs 6 LDS-admitted) -> KV-split(2).

typedef __attribute__((ext_vector_type(8))) __bf16 bf16x8;
typedef __attribute__((ext_vector_type(4))) __bf16 bf16x4;
typedef __attribute__((ext_vector_type(4))) float f32x4;

#define LOG2E 1.4426950408889634f

__device__ __forceinline__ f32x4 mfma16(bf16x8 a, bf16x8 b, f32x4 c) {
  return __builtin_amdgcn_mfma_f32_16x16x32_bf16(a, b, c, 0, 0, 0);
}

// global -> LDS direct copy, 16B per lane; LDS dest = wave-uniform base + lane*16.
__device__ __forceinline__ void gld16(const void* g, void* l) {
  auto* lp = reinterpret_cast<__attribute__((address_space(3))) uint32_t*>(
      reinterpret_cast<uintptr_t>(l));
  const auto* gp = reinterpret_cast<const __attribute__((address_space(1))) uint32_t*>(
      reinterpret_cast<uintptr_t>(g));
  __builtin_amdgcn_global_load_lds(gp, lp, 16, 0, 0);
}

// ---------------------------------------------------------------------------
// Fused prep: x f32->bf16, 6 weight transpose+converts (to [N][K] bf16), biases.
// ---------------------------------------------------------------------------
__device__ __forceinline__ void tr_tile(const float* in, __bf16* out, int R, int C,
                                        int bx, int by, float (*t)[33], int tid) {
  int tx = tid & 31, ty = tid >> 5;
  int r0 = by << 5, c0 = bx << 5;
#pragma unroll
  for (int i = 0; i < 4; i++)
    t[ty + i * 8][tx] = in[(size_t)(r0 + ty + i * 8) * C + c0 + tx];
  __syncthreads();
#pragma unroll
  for (int i = 0; i < 4; i++)
    out[(size_t)(c0 + ty + i * 8) * R + r0 + tx] = (__bf16)t[tx][ty + i * 8];
}

__global__ void __launch_bounds__(256) prep_kernel(
    const float* __restrict__ x, __bf16* __restrict__ xb,
    const float* __restrict__ Wdq, const float* __restrict__ Wdkv,
    const float* __restrict__ Wuq, const float* __restrict__ Wuk,
    const float* __restrict__ Wuv, const float* __restrict__ Wo,
    __bf16* __restrict__ Wcat, __bf16* __restrict__ Wuqkv, __bf16* __restrict__ Wot,
    const float* __restrict__ bdq, const float* __restrict__ bdkv,
    const float* __restrict__ buq, const float* __restrict__ buk,
    const float* __restrict__ buv, float* __restrict__ bcat, float* __restrict__ bqkv) {
  __shared__ float t[32][33];
  int bid = blockIdx.x;
  int tid = threadIdx.x;
  if (bid < 2048) {  // x -> bf16, 8 elems/thread
    int i = bid * 256 + tid;
    const f32x4* p = (const f32x4*)x + (size_t)i * 2;
    f32x4 a = p[0], b = p[1];
    bf16x8 o;
    o[0] = (__bf16)a[0]; o[1] = (__bf16)a[1]; o[2] = (__bf16)a[2]; o[3] = (__bf16)a[3];
    o[4] = (__bf16)b[0]; o[5] = (__bf16)b[1]; o[6] = (__bf16)b[2]; o[7] = (__bf16)b[3];
    ((bf16x8*)xb)[i] = o;
  } else if (bid < 2064) {  // biases
    int i = (bid - 2048) * 256 + tid;
    if (i < 1024) {
      bcat[i] = (i < 512) ? bdq[i] : bdkv[i - 512];
    } else {
      int j = i - 1024;  // 0..3071
      bqkv[j] = (j < 1024) ? buq[j] : (j < 2048 ? buk[j - 1024] : buv[j - 2048]);
    }
  } else {
    int t2 = bid - 2064;
    if (t2 < 512)        tr_tile(Wdq,  Wcat,                 1024, 512,  t2 & 15, t2 >> 4, t, tid);
    else if (t2 < 1024)  tr_tile(Wdkv, Wcat + 512 * 1024,    1024, 512,  (t2 - 512) & 15, (t2 - 512) >> 4, t, tid);
    else if (t2 < 1536)  tr_tile(Wuq,  Wuqkv,                512, 1024,  (t2 - 1024) & 31, (t2 - 1024) >> 5, t, tid);
    else if (t2 < 2048)  tr_tile(Wuk,  Wuqkv + 1024 * 512,   512, 1024,  (t2 - 1536) & 31, (t2 - 1536) >> 5, t, tid);
    else if (t2 < 2560)  tr_tile(Wuv,  Wuqkv + 2048 * 512,   512, 1024,  (t2 - 2048) & 31, (t2 - 2048) >> 5, t, tid);
    else                 tr_tile(Wo,   Wot,                  1024, 1024, (t2 - 2560) & 31, (t2 - 2560) >> 5, t, tid);
  }
}

// ---------------------------------------------------------------------------
// GEMM 128x128, BK=64, XOR-swizzled LDS (R14-verbatim).
// ---------------------------------------------------------------------------
__global__ void __launch_bounds__(256) gemm_bt(
    const __bf16* __restrict__ A, const __bf16* __restrict__ Bt,
    const float* __restrict__ bias, void* __restrict__ Cv,
    int N, int K, int lda, int ldb, int ldc, int aoff8, int outf32,
    __bf16* __restrict__ VtOut) {
  __shared__ __bf16 lA[128 * 64];
  __shared__ __bf16 lB[128 * 64];
  int bid = blockIdx.x, nwg = gridDim.x;
  int swz = (bid & 7) * (nwg >> 3) + (bid >> 3);  // XCD-aware (nwg % 8 == 0)
  int nbn = N >> 7;
  int tm = swz / nbn, tn = swz % nbn;
  int tid = threadIdx.x;
  int w = tid >> 6, lane = tid & 63;
  int wr = w >> 1, wc = w & 1;
  int c = lane & 15, g = lane >> 4;

  if (tn >= 8) A += aoff8;

  int sr = lane >> 3;
  int scs = ((lane & 7) ^ sr) * 8;
  const __bf16* aG[4]; const __bf16* bG[4];
  __bf16 *lAd[4], *lBd[4];
#pragma unroll
  for (int i = 0; i < 4; i++) {
    int c2 = w * 4 + i;
    aG[i] = A + (size_t)(tm * 128 + c2 * 8 + sr) * lda + scs;
    bG[i] = Bt + (size_t)(tn * 128 + c2 * 8 + sr) * ldb + scs;
    lAd[i] = &lA[c2 * 512];
    lBd[i] = &lB[c2 * 512];
  }

  const char* lAc = (const char*)lA;
  const char* lBc = (const char*)lB;
  int arow[4], brow[4];
#pragma unroll
  for (int m = 0; m < 4; m++) arow[m] = wr * 64 + m * 16 + c;
#pragma unroll
  for (int n = 0; n < 4; n++) brow[n] = wc * 64 + n * 16 + c;

  f32x4 acc[4][4] = {};
  int nk = K >> 6;
  for (int kt = 0; kt < nk; ++kt) {
#pragma unroll
    for (int i = 0; i < 4; i++) { gld16(aG[i], lAd[i]); gld16(bG[i], lBd[i]); }
#pragma unroll
    for (int i = 0; i < 4; i++) { aG[i] += 64; bG[i] += 64; }
    __syncthreads();
#pragma unroll
    for (int kk = 0; kk < 2; kk++) {
      bf16x8 af[4], bf[4];
#pragma unroll
      for (int m = 0; m < 4; m++)
        af[m] = *(const bf16x8*)(lAc + arow[m] * 128 +
                                 ((kk * 64 + g * 16) ^ ((arow[m] & 7) << 4)));
#pragma unroll
      for (int n = 0; n < 4; n++)
        bf[n] = *(const bf16x8*)(lBc + brow[n] * 128 +
                                 ((kk * 64 + g * 16) ^ ((brow[n] & 7) << 4)));
#pragma unroll
      for (int m = 0; m < 4; m++)
#pragma unroll
        for (int n = 0; n < 4; n++)
          acc[m][n] = mfma16(af[m], bf[n], acc[m][n]);
    }
    __syncthreads();
  }

  int row0 = tm * 128 + wr * 64 + g * 4;
  int col0 = tn * 128 + wc * 64 + c;
  if (VtOut && tn >= 16) {
#pragma unroll
    for (int n = 0; n < 4; n++) {
      int vd = col0 + n * 16 - 2048;
      float bv = bias[col0 + n * 16];
#pragma unroll
      for (int m = 0; m < 4; m++) {
        int rowg = row0 + m * 16;
        int bb = rowg >> 11, l = rowg & 2047;
        bf16x4 ov;
#pragma unroll
        for (int j = 0; j < 4; j++) ov[j] = (__bf16)(acc[m][n][j] + bv);
        *(bf16x4*)(VtOut + ((size_t)(bb * 1024 + vd)) * 2048 + l) = ov;
      }
    }
    return;
  }
#pragma unroll
  for (int n = 0; n < 4; n++) {
    int colg = col0 + n * 16;
    float bv = bias[colg];
#pragma unroll
    for (int m = 0; m < 4; m++) {
#pragma unroll
      for (int j = 0; j < 4; j++) {
        int rowg = row0 + m * 16 + j;
        float v = acc[m][n][j] + bv;
        if (outf32) ((float*)Cv)[(size_t)rowg * ldc + colg] = v;
        else ((__bf16*)Cv)[(size_t)rowg * ldc + colg] = (__bf16)v;
      }
    }
  }
}

// ---------------------------------------------------------------------------
// GEMM 128x64, BK=64, XOR-swizzled (R14-verbatim). 512 blocks = 2/CU.
// ---------------------------------------------------------------------------
__global__ void __launch_bounds__(256) gemm_bt64(
    const __bf16* __restrict__ A, const __bf16* __restrict__ Bt,
    const float* __restrict__ bias, void* __restrict__ Cv,
    int N, int K, int lda, int ldb, int ldc, int outf32) {
  __shared__ __bf16 lA[128 * 64];
  __shared__ __bf16 lB[64 * 64];
  int bid = blockIdx.x, nwg = gridDim.x;
  int swz = (bid & 7) * (nwg >> 3) + (bid >> 3);  // nwg % 8 == 0
  int nbn = N >> 6;
  int tm = swz / nbn, tn = swz % nbn;
  int tid = threadIdx.x;
  int w = tid >> 6, lane = tid & 63;
  int wr = w >> 1, wc = w & 1;
  int c = lane & 15, g = lane >> 4;

  int sr = lane >> 3;
  int scs = ((lane & 7) ^ sr) * 8;
  const __bf16* gsrc[6];
  __bf16* ldst[6];
#pragma unroll
  for (int i = 0; i < 6; i++) {
    int c2 = w * 6 + i;
    if (c2 < 16) {
      gsrc[i] = A + (size_t)(tm * 128 + c2 * 8 + sr) * lda + scs;
      ldst[i] = &lA[c2 * 512];
    } else {
      int d = c2 - 16;
      gsrc[i] = Bt + (size_t)(tn * 64 + d * 8 + sr) * ldb + scs;
      ldst[i] = &lB[d * 512];
    }
  }

  const char* lAc = (const char*)lA;
  const char* lBc = (const char*)lB;
  int arow[4], brow[2];
#pragma unroll
  for (int m = 0; m < 4; m++) arow[m] = wr * 64 + m * 16 + c;
#pragma unroll
  for (int n = 0; n < 2; n++) brow[n] = wc * 32 + n * 16 + c;

  f32x4 acc[4][2] = {};
  int nk = K >> 6;
  for (int kt = 0; kt < nk; ++kt) {
#pragma unroll
    for (int i = 0; i < 6; i++) gld16(gsrc[i], ldst[i]);
#pragma unroll
    for (int i = 0; i < 6; i++) gsrc[i] += 64;
    __syncthreads();
#pragma unroll
    for (int kk = 0; kk < 2; kk++) {
      bf16x8 af[4], bf[2];
#pragma unroll
      for (int m = 0; m < 4; m++)
        af[m] = *(const bf16x8*)(lAc + arow[m] * 128 +
                                 ((kk * 64 + g * 16) ^ ((arow[m] & 7) << 4)));
#pragma unroll
      for (int n = 0; n < 2; n++)
        bf[n] = *(const bf16x8*)(lBc + brow[n] * 128 +
                                 ((kk * 64 + g * 16) ^ ((brow[n] & 7) << 4)));
#pragma unroll
      for (int m = 0; m < 4; m++)
#pragma unroll
        for (int n = 0; n < 2; n++)
          acc[m][n] = mfma16(af[m], bf[n], acc[m][n]);
    }
    __syncthreads();
  }

  int row0 = tm * 128 + wr * 64 + g * 4;
  int col0 = tn * 64 + wc * 32 + c;
#pragma unroll
  for (int n = 0; n < 2; n++) {
    int colg = col0 + n * 16;
    float bv = bias[colg];
#pragma unroll
    for (int m = 0; m < 4; m++) {
#pragma unroll
      for (int j = 0; j < 4; j++) {
        int rowg = row0 + m * 16 + j;
        float v = acc[m][n][j] + bv;
        if (outf32) ((float*)Cv)[(size_t)rowg * ldc + colg] = v;
        else ((__bf16*)Cv)[(size_t)rowg * ldc + colg] = (__bf16)v;
      }
    }
  }
}

// ---------------------------------------------------------------------------
// Flash attention, KV-SPLIT(2) x R12-verbatim body. Grid 2048: bid = tile*2 +
// half (adjacent bids share a tile -> same XCD for K/V L2 reuse). Each block:
// 16 kt iters over its half. Static-max softmax means the merge needs NO max
// bookkeeping: O = (O0+O1)/(l0+l1). Partial O (unnormalized bf16) + lsum f32.
// Single K/V buffer, 25.6 KB -> up to 6 blocks/CU resident (grid now feeds 8).
// ---------------------------------------------------------------------------
__global__ void __launch_bounds__(256) attn64(const __bf16* __restrict__ QKV,
                                              const __bf16* __restrict__ Vt,
                                              __bf16* __restrict__ Opart,
                                              float* __restrict__ ml) {
  __shared__ __bf16 lK[64 * 64];
  __shared__ __bf16 lV[64 * 64];
  __shared__ __bf16 lP[4][16 * 72];

  int bid = blockIdx.x;                       // 2048
  int t = bid >> 1, half = bid & 1;
  int swz = (t & 7) * 128 + (t >> 3);         // XCD swizzle on tile index
  int bh = swz >> 5, qt = swz & 31;
  int b = bh >> 4, h = bh & 15;
  int kt0 = half * 16;

  int tid = threadIdx.x;
  int w = tid >> 6, lane = tid & 63;
  int c = lane & 15, g = lane >> 4;

  // Q frags (B-operand layout: col=q=c, k=d)
  const __bf16* qrow = QKV + (size_t)(b * 2048 + qt * 64 + w * 16 + c) * 3072 + h * 64;
  bf16x8 qf0 = *(const bf16x8*)(qrow + g * 8);
  bf16x8 qf1 = *(const bf16x8*)(qrow + 32 + g * 8);

  // staging: chunk c2 = w*2+i covers rows c2*8..+7 of the 64x128B tile
  int r0 = (w * 2 + 0) * 8 + (lane >> 3);
  int r1 = (w * 2 + 1) * 8 + (lane >> 3);
  int cc0 = ((lane & 7) ^ (r0 & 7)) * 8;  // pre-swizzled source col (involution)
  int cc1 = ((lane & 7) ^ (r1 & 7)) * 8;
  const __bf16* kG0 = QKV + (size_t)(b * 2048 + r0) * 3072 + 1024 + h * 64 + cc0;
  const __bf16* kG1 = QKV + (size_t)(b * 2048 + r1) * 3072 + 1024 + h * 64 + cc1;
  const __bf16* vtb = Vt + (size_t)bh * 64 * 2048;
  const __bf16* vG0 = vtb + (size_t)r0 * 2048 + cc0;
  const __bf16* vG1 = vtb + (size_t)r1 * 2048 + cc1;
  __bf16* lK0 = &lK[(w * 2 + 0) * 512];
  __bf16* lK1 = &lK[(w * 2 + 1) * 512];
  __bf16* lV0 = &lV[(w * 2 + 0) * 512];
  __bf16* lV1 = &lV[(w * 2 + 1) * 512];
  __bf16* myP = &lP[w][0];

  const char* lKc = (const char*)lK;
  const char* lVc = (const char*)lV;

  const float SC = 0.125f * LOG2E;  // 1/sqrt(64) folded into exp2 domain
  const float NM = -8.0f * SC;      // static max M=8 raw units (scores provably < 8)
  float lsumP = 0.f;                // per-lane partial; cross-lane reduce at end
  f32x4 o[4] = {};
  f32x4 zz = {0.f, 0.f, 0.f, 0.f};

  for (int kt = kt0; kt < kt0 + 16; ++kt) {
    gld16(kG0 + (size_t)kt * 64 * 3072, lK0);
    gld16(kG1 + (size_t)kt * 64 * 3072, lK1);
    gld16(vG0 + kt * 64, lV0);
    gld16(vG1 + kt * 64, lV1);
    __syncthreads();

    // S^T = K Q^T: sacc[n][j] = raw score at k = n*16+g*4+j, q = c
    f32x4 sacc[4];
#pragma unroll
    for (int n = 0; n < 4; n++) {
      int kr = n * 16 + c;
      bf16x8 k0 = *(const bf16x8*)(lKc + kr * 128 + ((g * 16) ^ ((kr & 7) << 4)));
      bf16x8 k1 = *(const bf16x8*)(lKc + kr * 128 + ((64 + g * 16) ^ ((kr & 7) << 4)));
      f32x4 s = mfma16(k0, qf0, zz);
      sacc[n] = mfma16(k1, qf1, s);
    }

    // V fragments -> registers NOW (no P dependency; latency hides under exp)
    bf16x8 vf0[4], vf1[4];
#pragma unroll
    for (int vr = 0; vr < 4; vr++) {
      int vrr = vr * 16 + c;
      vf0[vr] = *(const bf16x8*)(lVc + vrr * 128 + ((g * 16) ^ ((vrr & 7) << 4)));
      vf1[vr] = *(const bf16x8*)(lVc + vrr * 128 + ((64 + g * 16) ^ ((vrr & 7) << 4)));
    }

    // p = exp2(s*SC + NM); no max tracking, no per-iter cross-lane reduce
    float rs = 0.f;
#pragma unroll
    for (int n = 0; n < 4; n++) {
      bf16x4 pp;
#pragma unroll
      for (int j = 0; j < 4; j++) {
        float p = __builtin_amdgcn_exp2f(__builtin_fmaf(sacc[n][j], SC, NM));
        rs += p;
        pp[j] = (__bf16)p;
      }
      *(bf16x4*)&myP[c * 72 + n * 16 + g * 4] = pp;
    }
    lsumP += rs;
    bf16x8 pb0 = *(const bf16x8*)&myP[c * 72 + g * 8];
    bf16x8 pb1 = *(const bf16x8*)&myP[c * 72 + 32 + g * 8];

    // O^T += V^T P^T (V already in registers)
#pragma unroll
    for (int vr = 0; vr < 4; vr++) {
      o[vr] = mfma16(vf0[vr], pb0, o[vr]);
      o[vr] = mfma16(vf1[vr], pb1, o[vr]);
    }
    __syncthreads();
  }

  // cross-lane reduce of lsum (covers g-axis k partitions)
  float ls = lsumP;
  ls += __shfl_xor(ls, 16, 64);
  ls += __shfl_xor(ls, 32, 64);

  // epilogue: unnormalized partial O + per-row lsum; merge normalizes
  size_t prow = ((size_t)(half * 32 + bh) << 11) + qt * 64 + w * 16 + c;
  __bf16* op = Opart + prow * 64;
#pragma unroll
  for (int vr = 0; vr < 4; vr++) {
    bf16x4 ov;
#pragma unroll
    for (int j = 0; j < 4; j++) ov[j] = (__bf16)o[vr][j];
    *(bf16x4*)(op + vr * 16 + g * 4) = ov;
  }
  if (g == 0) ml[prow] = ls;
}

// ---------------------------------------------------------------------------
// Merge: O = (O0 + O1) / (l0 + l1). 2048 blocks x 256; thread -> (row, 8 d).
// ---------------------------------------------------------------------------
__global__ void __launch_bounds__(256) attn_merge(const __bf16* __restrict__ Opart,
                                                  const float* __restrict__ ml,
                                                  __bf16* __restrict__ AO) {
  int idx = blockIdx.x * 256 + threadIdx.x;  // 524288
  int row = idx >> 3, d8 = (idx & 7) * 8;
  float inv = 1.0f / (ml[row] + ml[65536 + row]);
  bf16x8 o0 = *(const bf16x8*)(Opart + (size_t)row * 64 + d8);
  bf16x8 o1 = *(const bf16x8*)(Opart + ((size_t)65536 + row) * 64 + d8);
  bf16x8 r;
#pragma unroll
  for (int j = 0; j < 8; j++)
    r[j] = (__bf16)(((float)o0[j] + (float)o1[j]) * inv);
  int bh = row >> 11, q = row & 2047;
  int b = bh >> 4, h = bh & 15;
  *(bf16x8*)(AO + ((size_t)(b * 2048 + q)) * 1024 + h * 64 + d8) = r;
}

// ---------------------------------------------------------------------------
extern "C" void kernel_launch(void* const* d_in, const int* in_sizes, int n_in,
                              void* d_out, int out_size, void* d_ws, size_t ws_size,
                              hipStream_t stream) {
  const float* x    = (const float*)d_in[0];
  const float* Wdq  = (const float*)d_in[2];
  const float* bdq  = (const float*)d_in[3];
  const float* Wdkv = (const float*)d_in[4];
  const float* bdkv = (const float*)d_in[5];
  const float* Wuq  = (const float*)d_in[6];
  const float* buq  = (const float*)d_in[7];
  const float* Wuk  = (const float*)d_in[8];
  const float* buk  = (const float*)d_in[9];
  const float* Wuv  = (const float*)d_in[10];
  const float* buv  = (const float*)d_in[11];
  const float* Wo   = (const float*)d_in[12];
  const float* bo   = (const float*)d_in[13];

  char* ws = (char*)d_ws;
  const size_t MB = 1024 * 1024;
  __bf16* xb    = (__bf16*)(ws);             //  8 MB (dead after gemm1)
  __bf16* Dlat  = (__bf16*)(ws + 8 * MB);    //  8 MB (dead after gemm2)
  __bf16* QKV   = (__bf16*)(ws + 16 * MB);   // 24 MB (V region unused; Vt direct)
  __bf16* Vt    = (__bf16*)(ws + 40 * MB);   //  8 MB
  __bf16* AO    = (__bf16*)(ws + 48 * MB);   //  8 MB
  __bf16* Wcat  = (__bf16*)(ws + 56 * MB);   //  2 MB (dead after gemm1)
  __bf16* Wuqkv = (__bf16*)(ws + 58 * MB);   //  3 MB
  __bf16* Wot   = (__bf16*)(ws + 61 * MB);   //  2 MB
  float*  bcat  = (float*)(ws + 63 * MB);
  float*  bqkv  = (float*)(ws + 63 * MB + 16384);
  __bf16* Opart = (__bf16*)(ws);             // 16 MB, reuses xb+Dlat
  float*  ml    = (float*)(ws + 56 * MB);    // 512 KB, reuses Wcat

  prep_kernel<<<5648, 256, 0, stream>>>(x, xb, Wdq, Wdkv, Wuq, Wuk, Wuv, Wo,
                                        Wcat, Wuqkv, Wot, bdq, bdkv, buq, buk, buv,
                                        bcat, bqkv);
  // Dlat = x @ [Wdq|Wdkv] + [bdq|bdkv]   (128x64 tiles, BK=64: 512 blocks)
  gemm_bt64<<<512, 256, 0, stream>>>(xb, Wcat, bcat, Dlat, 1024, 1024, 1024, 1024, 1024, 0);
  // QKV = [DQ@Wuq | DKV@Wuk | DKV@Wuv] + biases; V tiles written transposed into Vt
  gemm_bt<<<768, 256, 0, stream>>>(Dlat, Wuqkv, bqkv, QKV, 3072, 512, 1024, 512, 3072, 512, 0, Vt);
  attn64<<<2048, 256, 0, stream>>>(QKV, Vt, Opart, ml);
  attn_merge<<<2048, 256, 0, stream>>>(Opart, ml, AO);
  // out = AO @ Wo + bo  (f32, 128x64 tiles, BK=64)
  gemm_bt64<<<512, 256, 0, stream>>>(AO, Wot, bo, (float*)d_out, 1024, 1024, 1024, 1024, 1024, 1);
}

// Round 17
// 115.920 us; speedup vs baseline: 1.1269x; 1.1269x over previous
//
#include <hip/hip_runtime.h>
#include <hip/hip_bf16.h>
#include <stdint.h>
#include <math.h>

// MLA: B=2, L=2048, D=1024, H=16, DH=64, DC=512. All f32 in/out; bf16 MFMA inside.
// SESSION LESSONS:
//  (R11) LDS stride for bf16 vector ds ops MUST be a multiple of 8 elements.
//  (R8/R12/R13/R16) attn closed at ~66 µs: 16q/wave x 4-wave x grid1024;
//        qg=2, 2-wave, KV-split, dbuf all neutral-to-worse. Plateau intrinsic.
//  (R3) no runtime-indexed LDS buffers; (R6/R11) no hot-loop branches.
//  (R14) GEMM BK=64 + XOR swizzle: conflict-free frag reads, half barriers.
//  (R17) gemm_bt64 dbuf is occupancy-FREE (grid 512 caps at 2/CU anyway;
//        48 KB LDS still admits 2) -> hide staging latency there.

typedef __attribute__((ext_vector_type(8))) __bf16 bf16x8;
typedef __attribute__((ext_vector_type(4))) __bf16 bf16x4;
typedef __attribute__((ext_vector_type(4))) float f32x4;

#define LOG2E 1.4426950408889634f

__device__ __forceinline__ f32x4 mfma16(bf16x8 a, bf16x8 b, f32x4 c) {
  return __builtin_amdgcn_mfma_f32_16x16x32_bf16(a, b, c, 0, 0, 0);
}

// global -> LDS direct copy, 16B per lane; LDS dest = wave-uniform base + lane*16.
__device__ __forceinline__ void gld16(const void* g, void* l) {
  auto* lp = reinterpret_cast<__attribute__((address_space(3))) uint32_t*>(
      reinterpret_cast<uintptr_t>(l));
  const auto* gp = reinterpret_cast<const __attribute__((address_space(1))) uint32_t*>(
      reinterpret_cast<uintptr_t>(g));
  __builtin_amdgcn_global_load_lds(gp, lp, 16, 0, 0);
}

// ---------------------------------------------------------------------------
// Fused prep: x f32->bf16, 6 weight transpose+converts (to [N][K] bf16), biases.
// ---------------------------------------------------------------------------
__device__ __forceinline__ void tr_tile(const float* in, __bf16* out, int R, int C,
                                        int bx, int by, float (*t)[33], int tid) {
  int tx = tid & 31, ty = tid >> 5;
  int r0 = by << 5, c0 = bx << 5;
#pragma unroll
  for (int i = 0; i < 4; i++)
    t[ty + i * 8][tx] = in[(size_t)(r0 + ty + i * 8) * C + c0 + tx];
  __syncthreads();
#pragma unroll
  for (int i = 0; i < 4; i++)
    out[(size_t)(c0 + ty + i * 8) * R + r0 + tx] = (__bf16)t[tx][ty + i * 8];
}

__global__ void __launch_bounds__(256) prep_kernel(
    const float* __restrict__ x, __bf16* __restrict__ xb,
    const float* __restrict__ Wdq, const float* __restrict__ Wdkv,
    const float* __restrict__ Wuq, const float* __restrict__ Wuk,
    const float* __restrict__ Wuv, const float* __restrict__ Wo,
    __bf16* __restrict__ Wcat, __bf16* __restrict__ Wuqkv, __bf16* __restrict__ Wot,
    const float* __restrict__ bdq, const float* __restrict__ bdkv,
    const float* __restrict__ buq, const float* __restrict__ buk,
    const float* __restrict__ buv, float* __restrict__ bcat, float* __restrict__ bqkv) {
  __shared__ float t[32][33];
  int bid = blockIdx.x;
  int tid = threadIdx.x;
  if (bid < 2048) {  // x -> bf16, 8 elems/thread
    int i = bid * 256 + tid;
    const f32x4* p = (const f32x4*)x + (size_t)i * 2;
    f32x4 a = p[0], b = p[1];
    bf16x8 o;
    o[0] = (__bf16)a[0]; o[1] = (__bf16)a[1]; o[2] = (__bf16)a[2]; o[3] = (__bf16)a[3];
    o[4] = (__bf16)b[0]; o[5] = (__bf16)b[1]; o[6] = (__bf16)b[2]; o[7] = (__bf16)b[3];
    ((bf16x8*)xb)[i] = o;
  } else if (bid < 2064) {  // biases
    int i = (bid - 2048) * 256 + tid;
    if (i < 1024) {
      bcat[i] = (i < 512) ? bdq[i] : bdkv[i - 512];
    } else {
      int j = i - 1024;  // 0..3071
      bqkv[j] = (j < 1024) ? buq[j] : (j < 2048 ? buk[j - 1024] : buv[j - 2048]);
    }
  } else {
    int t2 = bid - 2064;
    if (t2 < 512)        tr_tile(Wdq,  Wcat,                 1024, 512,  t2 & 15, t2 >> 4, t, tid);
    else if (t2 < 1024)  tr_tile(Wdkv, Wcat + 512 * 1024,    1024, 512,  (t2 - 512) & 15, (t2 - 512) >> 4, t, tid);
    else if (t2 < 1536)  tr_tile(Wuq,  Wuqkv,                512, 1024,  (t2 - 1024) & 31, (t2 - 1024) >> 5, t, tid);
    else if (t2 < 2048)  tr_tile(Wuk,  Wuqkv + 1024 * 512,   512, 1024,  (t2 - 1536) & 31, (t2 - 1536) >> 5, t, tid);
    else if (t2 < 2560)  tr_tile(Wuv,  Wuqkv + 2048 * 512,   512, 1024,  (t2 - 2048) & 31, (t2 - 2048) >> 5, t, tid);
    else                 tr_tile(Wo,   Wot,                  1024, 1024, (t2 - 2560) & 31, (t2 - 2560) >> 5, t, tid);
  }
}

// ---------------------------------------------------------------------------
// GEMM 128x128, BK=64, XOR-swizzled LDS (R14-verbatim).
// ---------------------------------------------------------------------------
__global__ void __launch_bounds__(256) gemm_bt(
    const __bf16* __restrict__ A, const __bf16* __restrict__ Bt,
    const float* __restrict__ bias, void* __restrict__ Cv,
    int N, int K, int lda, int ldb, int ldc, int aoff8, int outf32,
    __bf16* __restrict__ VtOut) {
  __shared__ __bf16 lA[128 * 64];
  __shared__ __bf16 lB[128 * 64];
  int bid = blockIdx.x, nwg = gridDim.x;
  int swz = (bid & 7) * (nwg >> 3) + (bid >> 3);  // XCD-aware (nwg % 8 == 0)
  int nbn = N >> 7;
  int tm = swz / nbn, tn = swz % nbn;
  int tid = threadIdx.x;
  int w = tid >> 6, lane = tid & 63;
  int wr = w >> 1, wc = w & 1;
  int c = lane & 15, g = lane >> 4;

  if (tn >= 8) A += aoff8;

  int sr = lane >> 3;
  int scs = ((lane & 7) ^ sr) * 8;
  const __bf16* aG[4]; const __bf16* bG[4];
  __bf16 *lAd[4], *lBd[4];
#pragma unroll
  for (int i = 0; i < 4; i++) {
    int c2 = w * 4 + i;
    aG[i] = A + (size_t)(tm * 128 + c2 * 8 + sr) * lda + scs;
    bG[i] = Bt + (size_t)(tn * 128 + c2 * 8 + sr) * ldb + scs;
    lAd[i] = &lA[c2 * 512];
    lBd[i] = &lB[c2 * 512];
  }

  const char* lAc = (const char*)lA;
  const char* lBc = (const char*)lB;
  int arow[4], brow[4];
#pragma unroll
  for (int m = 0; m < 4; m++) arow[m] = wr * 64 + m * 16 + c;
#pragma unroll
  for (int n = 0; n < 4; n++) brow[n] = wc * 64 + n * 16 + c;

  f32x4 acc[4][4] = {};
  int nk = K >> 6;
  for (int kt = 0; kt < nk; ++kt) {
#pragma unroll
    for (int i = 0; i < 4; i++) { gld16(aG[i], lAd[i]); gld16(bG[i], lBd[i]); }
#pragma unroll
    for (int i = 0; i < 4; i++) { aG[i] += 64; bG[i] += 64; }
    __syncthreads();
#pragma unroll
    for (int kk = 0; kk < 2; kk++) {
      bf16x8 af[4], bf[4];
#pragma unroll
      for (int m = 0; m < 4; m++)
        af[m] = *(const bf16x8*)(lAc + arow[m] * 128 +
                                 ((kk * 64 + g * 16) ^ ((arow[m] & 7) << 4)));
#pragma unroll
      for (int n = 0; n < 4; n++)
        bf[n] = *(const bf16x8*)(lBc + brow[n] * 128 +
                                 ((kk * 64 + g * 16) ^ ((brow[n] & 7) << 4)));
#pragma unroll
      for (int m = 0; m < 4; m++)
#pragma unroll
        for (int n = 0; n < 4; n++)
          acc[m][n] = mfma16(af[m], bf[n], acc[m][n]);
    }
    __syncthreads();
  }

  int row0 = tm * 128 + wr * 64 + g * 4;
  int col0 = tn * 128 + wc * 64 + c;
  if (VtOut && tn >= 16) {
#pragma unroll
    for (int n = 0; n < 4; n++) {
      int vd = col0 + n * 16 - 2048;
      float bv = bias[col0 + n * 16];
#pragma unroll
      for (int m = 0; m < 4; m++) {
        int rowg = row0 + m * 16;
        int bb = rowg >> 11, l = rowg & 2047;
        bf16x4 ov;
#pragma unroll
        for (int j = 0; j < 4; j++) ov[j] = (__bf16)(acc[m][n][j] + bv);
        *(bf16x4*)(VtOut + ((size_t)(bb * 1024 + vd)) * 2048 + l) = ov;
      }
    }
    return;
  }
#pragma unroll
  for (int n = 0; n < 4; n++) {
    int colg = col0 + n * 16;
    float bv = bias[colg];
#pragma unroll
    for (int m = 0; m < 4; m++) {
#pragma unroll
      for (int j = 0; j < 4; j++) {
        int rowg = row0 + m * 16 + j;
        float v = acc[m][n][j] + bv;
        if (outf32) ((float*)Cv)[(size_t)rowg * ldc + colg] = v;
        else ((__bf16*)Cv)[(size_t)rowg * ldc + colg] = (__bf16)v;
      }
    }
  }
}

// ---------------------------------------------------------------------------
// GEMM 128x64, BK=64, XOR-swizzled + STATIC DOUBLE BUFFER (R17): grid 512
// caps residency at 2 blocks/CU regardless, and 48 KB LDS still admits 2 ->
// dbuf hides the per-kt staging latency at zero occupancy cost. Buffers are
// distinct named symbols; loop 2x-unrolled (no runtime indexing, R3 lesson).
// ---------------------------------------------------------------------------
__global__ void __launch_bounds__(256) gemm_bt64(
    const __bf16* __restrict__ A, const __bf16* __restrict__ Bt,
    const float* __restrict__ bias, void* __restrict__ Cv,
    int N, int K, int lda, int ldb, int ldc, int outf32) {
  __shared__ __bf16 lAa[128 * 64];
  __shared__ __bf16 lAb[128 * 64];
  __shared__ __bf16 lBa[64 * 64];
  __shared__ __bf16 lBb[64 * 64];
  int bid = blockIdx.x, nwg = gridDim.x;
  int swz = (bid & 7) * (nwg >> 3) + (bid >> 3);  // nwg % 8 == 0
  int nbn = N >> 6;
  int tm = swz / nbn, tn = swz % nbn;
  int tid = threadIdx.x;
  int w = tid >> 6, lane = tid & 63;
  int wr = w >> 1, wc = w & 1;
  int c = lane & 15, g = lane >> 4;

  int sr = lane >> 3;
  int scs = ((lane & 7) ^ sr) * 8;
  // chunks: c2 = w*6+i; c2<16 -> A rows c2*8..+7; else B rows (c2-16)*8..+7
  const __bf16* gsrc[6];
  int off[6];
  bool isA[6];
#pragma unroll
  for (int i = 0; i < 6; i++) {
    int c2 = w * 6 + i;
    isA[i] = (c2 < 16);
    if (isA[i]) {
      gsrc[i] = A + (size_t)(tm * 128 + c2 * 8 + sr) * lda + scs;
      off[i] = c2 * 512;
    } else {
      int d = c2 - 16;
      gsrc[i] = Bt + (size_t)(tn * 64 + d * 8 + sr) * ldb + scs;
      off[i] = d * 512;
    }
  }

  int arow[4], brow[2];
#pragma unroll
  for (int m = 0; m < 4; m++) arow[m] = wr * 64 + m * 16 + c;
#pragma unroll
  for (int n = 0; n < 2; n++) brow[n] = wc * 32 + n * 16 + c;

  f32x4 acc[4][2] = {};

  auto stage = [&](__bf16* Ab, __bf16* Bb) {
#pragma unroll
    for (int i = 0; i < 6; i++) gld16(gsrc[i], (isA[i] ? Ab : Bb) + off[i]);
#pragma unroll
    for (int i = 0; i < 6; i++) gsrc[i] += 64;
  };

  auto compute = [&](const __bf16* Ab, const __bf16* Bb) {
    const char* Ac = (const char*)Ab;
    const char* Bc = (const char*)Bb;
#pragma unroll
    for (int kk = 0; kk < 2; kk++) {
      bf16x8 af[4], bf[2];
#pragma unroll
      for (int m = 0; m < 4; m++)
        af[m] = *(const bf16x8*)(Ac + arow[m] * 128 +
                                 ((kk * 64 + g * 16) ^ ((arow[m] & 7) << 4)));
#pragma unroll
      for (int n = 0; n < 2; n++)
        bf[n] = *(const bf16x8*)(Bc + brow[n] * 128 +
                                 ((kk * 64 + g * 16) ^ ((brow[n] & 7) << 4)));
#pragma unroll
      for (int m = 0; m < 4; m++)
#pragma unroll
        for (int n = 0; n < 2; n++)
          acc[m][n] = mfma16(af[m], bf[n], acc[m][n]);
    }
  };

  int nk = K >> 6;  // 16 for K=1024 (even)
  stage(lAa, lBa);
  for (int kt2 = 0; kt2 < nk / 2; ++kt2) {
    __syncthreads();                       // A landed; everyone done reading B
    stage(lAb, lBb);                       // latency hides under compute(A)
    compute(lAa, lBa);
    __syncthreads();                       // B landed; everyone done reading A
    if (kt2 * 2 + 2 < nk) stage(lAa, lBa);
    compute(lAb, lBb);
  }

  int row0 = tm * 128 + wr * 64 + g * 4;
  int col0 = tn * 64 + wc * 32 + c;
#pragma unroll
  for (int n = 0; n < 2; n++) {
    int colg = col0 + n * 16;
    float bv = bias[colg];
#pragma unroll
    for (int m = 0; m < 4; m++) {
#pragma unroll
      for (int j = 0; j < 4; j++) {
        int rowg = row0 + m * 16 + j;
        float v = acc[m][n][j] + bv;
        if (outf32) ((float*)Cv)[(size_t)rowg * ldc + colg] = v;
        else ((__bf16*)Cv)[(size_t)rowg * ldc + colg] = (__bf16)v;
      }
    }
  }
}

// ---------------------------------------------------------------------------
// Flash attention — VERBATIM R12 (65.9 µs best): static-max softmax, deferred
// lsum, V-hoist, stride-72 P, 16q/wave, 4 waves, grid 1024, single buffer.
// ---------------------------------------------------------------------------
__global__ void __launch_bounds__(256) attn64(const __bf16* __restrict__ QKV,
                                              const __bf16* __restrict__ Vt,
                                              __bf16* __restrict__ AO) {
  __shared__ __bf16 lK[64 * 64];
  __shared__ __bf16 lV[64 * 64];
  __shared__ __bf16 lP[4][16 * 72];

  int bid = blockIdx.x;                       // 1024
  int swz = (bid & 7) * 128 + (bid >> 3);     // XCD swizzle
  int bh = swz >> 5, qt = swz & 31;
  int b = bh >> 4, h = bh & 15;

  int tid = threadIdx.x;
  int w = tid >> 6, lane = tid & 63;
  int c = lane & 15, g = lane >> 4;

  // Q frags (B-operand layout: col=q=c, k=d)
  const __bf16* qrow = QKV + (size_t)(b * 2048 + qt * 64 + w * 16 + c) * 3072 + h * 64;
  bf16x8 qf0 = *(const bf16x8*)(qrow + g * 8);
  bf16x8 qf1 = *(const bf16x8*)(qrow + 32 + g * 8);

  // staging: chunk c2 = w*2+i covers rows c2*8..+7 of the 64x128B tile
  int r0 = (w * 2 + 0) * 8 + (lane >> 3);
  int r1 = (w * 2 + 1) * 8 + (lane >> 3);
  int cc0 = ((lane & 7) ^ (r0 & 7)) * 8;  // pre-swizzled source col (involution)
  int cc1 = ((lane & 7) ^ (r1 & 7)) * 8;
  const __bf16* kG0 = QKV + (size_t)(b * 2048 + r0) * 3072 + 1024 + h * 64 + cc0;
  const __bf16* kG1 = QKV + (size_t)(b * 2048 + r1) * 3072 + 1024 + h * 64 + cc1;
  const __bf16* vtb = Vt + (size_t)bh * 64 * 2048;
  const __bf16* vG0 = vtb + (size_t)r0 * 2048 + cc0;
  const __bf16* vG1 = vtb + (size_t)r1 * 2048 + cc1;
  __bf16* lK0 = &lK[(w * 2 + 0) * 512];
  __bf16* lK1 = &lK[(w * 2 + 1) * 512];
  __bf16* lV0 = &lV[(w * 2 + 0) * 512];
  __bf16* lV1 = &lV[(w * 2 + 1) * 512];
  __bf16* myP = &lP[w][0];

  const char* lKc = (const char*)lK;
  const char* lVc = (const char*)lV;

  const float SC = 0.125f * LOG2E;  // 1/sqrt(64) folded into exp2 domain
  const float NM = -8.0f * SC;      // static max M=8 raw units (scores provably < 8)
  float lsumP = 0.f;                // per-lane partial; cross-lane reduce at end
  f32x4 o[4] = {};
  f32x4 zz = {0.f, 0.f, 0.f, 0.f};

  for (int kt = 0; kt < 32; ++kt) {
    gld16(kG0 + (size_t)kt * 64 * 3072, lK0);
    gld16(kG1 + (size_t)kt * 64 * 3072, lK1);
    gld16(vG0 + kt * 64, lV0);
    gld16(vG1 + kt * 64, lV1);
    __syncthreads();

    // S^T = K Q^T: sacc[n][j] = raw score at k = n*16+g*4+j, q = c
    f32x4 sacc[4];
#pragma unroll
    for (int n = 0; n < 4; n++) {
      int kr = n * 16 + c;
      bf16x8 k0 = *(const bf16x8*)(lKc + kr * 128 + ((g * 16) ^ ((kr & 7) << 4)));
      bf16x8 k1 = *(const bf16x8*)(lKc + kr * 128 + ((64 + g * 16) ^ ((kr & 7) << 4)));
      f32x4 s = mfma16(k0, qf0, zz);
      sacc[n] = mfma16(k1, qf1, s);
    }

    // V fragments -> registers NOW (no P dependency; latency hides under exp)
    bf16x8 vf0[4], vf1[4];
#pragma unroll
    for (int vr = 0; vr < 4; vr++) {
      int vrr = vr * 16 + c;
      vf0[vr] = *(const bf16x8*)(lVc + vrr * 128 + ((g * 16) ^ ((vrr & 7) << 4)));
      vf1[vr] = *(const bf16x8*)(lVc + vrr * 128 + ((64 + g * 16) ^ ((vrr & 7) << 4)));
    }

    // p = exp2(s*SC + NM); no max tracking, no per-iter cross-lane reduce
    float rs = 0.f;
#pragma unroll
    for (int n = 0; n < 4; n++) {
      bf16x4 pp;
#pragma unroll
      for (int j = 0; j < 4; j++) {
        float p = __builtin_amdgcn_exp2f(__builtin_fmaf(sacc[n][j], SC, NM));
        rs += p;
        pp[j] = (__bf16)p;
      }
      *(bf16x4*)&myP[c * 72 + n * 16 + g * 4] = pp;
    }
    lsumP += rs;
    bf16x8 pb0 = *(const bf16x8*)&myP[c * 72 + g * 8];
    bf16x8 pb1 = *(const bf16x8*)&myP[c * 72 + 32 + g * 8];

    // O^T += V^T P^T (V already in registers)
#pragma unroll
    for (int vr = 0; vr < 4; vr++) {
      o[vr] = mfma16(vf0[vr], pb0, o[vr]);
      o[vr] = mfma16(vf1[vr], pb1, o[vr]);
    }
    __syncthreads();
  }

  // one cross-lane reduce for the whole kernel (covers g-axis k partitions)
  float ls = lsumP;
  ls += __shfl_xor(ls, 16, 64);
  ls += __shfl_xor(ls, 32, 64);
  float inv = 1.0f / ls;  // q = c, lane-local
  __bf16* aor = AO + (size_t)(b * 2048 + qt * 64 + w * 16 + c) * 1024 + h * 64;
#pragma unroll
  for (int vr = 0; vr < 4; vr++) {
    bf16x4 ov;
#pragma unroll
    for (int j = 0; j < 4; j++) ov[j] = (__bf16)(o[vr][j] * inv);
    *(bf16x4*)(aor + vr * 16 + g * 4) = ov;
  }
}

// ---------------------------------------------------------------------------
extern "C" void kernel_launch(void* const* d_in, const int* in_sizes, int n_in,
                              void* d_out, int out_size, void* d_ws, size_t ws_size,
                              hipStream_t stream) {
  const float* x    = (const float*)d_in[0];
  const float* Wdq  = (const float*)d_in[2];
  const float* bdq  = (const float*)d_in[3];
  const float* Wdkv = (const float*)d_in[4];
  const float* bdkv = (const float*)d_in[5];
  const float* Wuq  = (const float*)d_in[6];
  const float* buq  = (const float*)d_in[7];
  const float* Wuk  = (const float*)d_in[8];
  const float* buk  = (const float*)d_in[9];
  const float* Wuv  = (const float*)d_in[10];
  const float* buv  = (const float*)d_in[11];
  const float* Wo   = (const float*)d_in[12];
  const float* bo   = (const float*)d_in[13];

  char* ws = (char*)d_ws;
  const size_t MB = 1024 * 1024;
  __bf16* xb    = (__bf16*)(ws);             //  8 MB
  __bf16* Dlat  = (__bf16*)(ws + 8 * MB);    //  8 MB
  __bf16* QKV   = (__bf16*)(ws + 16 * MB);   // 24 MB (V region unused; Vt direct)
  __bf16* Vt    = (__bf16*)(ws + 40 * MB);   //  8 MB
  __bf16* AO    = (__bf16*)(ws + 48 * MB);   //  8 MB
  __bf16* Wcat  = (__bf16*)(ws + 56 * MB);   //  2 MB
  __bf16* Wuqkv = (__bf16*)(ws + 58 * MB);   //  3 MB
  __bf16* Wot   = (__bf16*)(ws + 61 * MB);   //  2 MB
  float*  bcat  = (float*)(ws + 63 * MB);
  float*  bqkv  = (float*)(ws + 63 * MB + 16384);

  prep_kernel<<<5648, 256, 0, stream>>>(x, xb, Wdq, Wdkv, Wuq, Wuk, Wuv, Wo,
                                        Wcat, Wuqkv, Wot, bdq, bdkv, buq, buk, buv,
                                        bcat, bqkv);
  // Dlat = x @ [Wdq|Wdkv] + [bdq|bdkv]   (128x64 tiles, BK=64 dbuf: 512 blocks)
  gemm_bt64<<<512, 256, 0, stream>>>(xb, Wcat, bcat, Dlat, 1024, 1024, 1024, 1024, 1024, 0);
  // QKV = [DQ@Wuq | DKV@Wuk | DKV@Wuv] + biases; V tiles written transposed into Vt
  gemm_bt<<<768, 256, 0, stream>>>(Dlat, Wuqkv, bqkv, QKV, 3072, 512, 1024, 512, 3072, 512, 0, Vt);
  attn64<<<1024, 256, 0, stream>>>(QKV, Vt, AO);
  // out = AO @ Wo + bo  (f32, 128x64 tiles, BK=64 dbuf)
  gemm_bt64<<<512, 256, 0, stream>>>(AO, Wot, bo, (float*)d_out, 1024, 1024, 1024, 1024, 1024, 1);
}